// Round 1
// 140.909 us; speedup vs baseline: 1.0710x; 1.0710x over previous
//
#include <hip/hip_runtime.h>
#include <cmath>

// Problem constants
#define Bn 4
#define Sn 2048
#define En 256
#define Hn 8
#define Dn 32
#define KD 256          // inner GEMM dim (= En)
#define NS 16           // key splits for attention
#define CHUNK 128       // keys per split

static constexpr float SCALE_F = 0.17677669529663687f;  // 32^-0.5
// SCALE * log2(e): Q is pre-scaled so attn can use raw v_exp_f32 (exp2)
static constexpr float SCALE_LOG2E = 0.25504210472155044f;

typedef _Float16 half4_t __attribute__((ext_vector_type(4)));
typedef _Float16 half8_t __attribute__((ext_vector_type(8)));
typedef float float4_t __attribute__((ext_vector_type(4)));

// ---------- lengths[b] = sum(mask[b,:]) ----------
__global__ __launch_bounds__(256) void len_kernel(const int* __restrict__ mask,
                                                  int* __restrict__ len) {
  int b = blockIdx.x, t = threadIdx.x;
  int s = 0;
  for (int i = t; i < Sn; i += 256) s += mask[b * Sn + i];
#pragma unroll
  for (int off = 32; off > 0; off >>= 1) s += __shfl_down(s, off, 64);
  __shared__ int red[4];
  if ((t & 63) == 0) red[t >> 6] = s;
  __syncthreads();
  if (t == 0) len[b] = red[0] + red[1] + red[2] + red[3];
}

// ---------- fp32 -> f16 convert: x (2M) then Wq|Wk|Wv|Wo (64K each) ----------
__global__ __launch_bounds__(256) void cvt_kernel(
    const float* __restrict__ x, const float* __restrict__ Wq,
    const float* __restrict__ Wk, const float* __restrict__ Wv,
    const float* __restrict__ Wo, _Float16* __restrict__ xh,
    _Float16* __restrict__ Wh) {
  const size_t base = ((size_t)blockIdx.x * 256 + threadIdx.x) * 8;
  const float* src; _Float16* dst; size_t off;
  if (base < 2097152) { src = x; dst = xh; off = base; }
  else {
    size_t wi = base - 2097152;        // 0 .. 262143
    int w = (int)(wi >> 16);           // 0..3
    off = wi & 65535;
    src = (w == 0) ? Wq : (w == 1) ? Wk : (w == 2) ? Wv : Wo;
    dst = Wh + (size_t)w * 65536;
  }
  float4 a = *(const float4*)&src[off];
  float4 b2 = *(const float4*)&src[off + 4];
  half8_t h;
  h[0] = (_Float16)a.x;  h[1] = (_Float16)a.y;
  h[2] = (_Float16)a.z;  h[3] = (_Float16)a.w;
  h[4] = (_Float16)b2.x; h[5] = (_Float16)b2.y;
  h[6] = (_Float16)b2.z; h[7] = (_Float16)b2.w;
  *(half8_t*)&dst[off] = h;
}

// ---------- QKV MFMA GEMM: [8192,256]f16 @ [768,256]^T f16 ----------
// V written in TILED transpose layout: VT[bh][kblk][d][k&31] (2KB tiles).
__global__ __launch_bounds__(256) void qkv_gemm(
    const _Float16* __restrict__ xh, const _Float16* __restrict__ Wh,
    _Float16* __restrict__ Qh, _Float16* __restrict__ Kh,
    _Float16* __restrict__ Vt) {
  const int lane = threadIdx.x & 63;
  const int wv = threadIdx.x >> 6;
  const int quad = lane >> 4, l15 = lane & 15;
  const int n0 = blockIdx.x * 64;          // matrix = n0>>8, uniform per block
  const int mw = blockIdx.y * 256 + wv * 64;

  float4_t C[4][4];
#pragma unroll
  for (int i = 0; i < 4; ++i)
#pragma unroll
    for (int j = 0; j < 4; ++j) C[i][j] = (float4_t){0.f, 0.f, 0.f, 0.f};

  for (int k0 = 0; k0 < KD; k0 += 32) {
    half8_t A[4], Bf[4];
#pragma unroll
    for (int i = 0; i < 4; ++i)
      A[i] = *(const half8_t*)&xh[(size_t)(mw + 16 * i + l15) * KD + k0 + quad * 8];
#pragma unroll
    for (int j = 0; j < 4; ++j)
      Bf[j] = *(const half8_t*)&Wh[(size_t)(n0 + 16 * j + l15) * KD + k0 + quad * 8];
#pragma unroll
    for (int i = 0; i < 4; ++i)
#pragma unroll
      for (int j = 0; j < 4; ++j)
        C[i][j] = __builtin_amdgcn_mfma_f32_16x16x32_f16(A[i], Bf[j], C[i][j], 0, 0, 0);
  }

  const int mat = n0 >> 8;
  if (mat < 2) {
    _Float16* dstH = mat ? Kh : Qh;
    const float scale = mat ? 1.0f : SCALE_LOG2E;  // fold softmax scale * log2e into Q
#pragma unroll
    for (int i = 0; i < 4; ++i)
#pragma unroll
      for (int j = 0; j < 4; ++j) {
        const int c = ((n0 + 16 * j) & 255) + l15;
        const int h = c >> 5, d = c & 31;
#pragma unroll
        for (int r = 0; r < 4; ++r) {
          const int m = mw + 16 * i + quad * 4 + r;
          const int b = m >> 11, s = m & (Sn - 1);
          dstH[((size_t)(b * Hn + h) * Sn + s) * Dn + d] =
              (_Float16)(C[i][j][r] * scale);
        }
      }
  } else {
#pragma unroll
    for (int i = 0; i < 4; ++i)
#pragma unroll
      for (int j = 0; j < 4; ++j) {
        const int c = ((n0 + 16 * j) & 255) + l15;
        const int h = c >> 5, d = c & 31;
        const int m = mw + 16 * i + quad * 4;   // 4 consecutive s, same 32-tile
        const int b = m >> 11, s = m & (Sn - 1);
        half4_t hv;
#pragma unroll
        for (int r = 0; r < 4; ++r) hv[r] = (_Float16)C[i][j][r];
        *(half4_t*)&Vt[(size_t)(b * Hn + h) * (Sn * Dn) +
                       (size_t)(s >> 5) * 1024 + d * 32 + (s & 31)] = hv;
      }
  }
}

// ---------- output MFMA GEMM: [8192,256]f16 (Ph) @ Wo^T f16 -> fp32 d_out ----------
__global__ __launch_bounds__(256) void out_gemm(
    const _Float16* __restrict__ Ph, const _Float16* __restrict__ Woh,
    float* __restrict__ out) {
  const int lane = threadIdx.x & 63;
  const int wv = threadIdx.x >> 6;
  const int quad = lane >> 4, l15 = lane & 15;
  const int n0 = blockIdx.x * 64;
  const int mw = blockIdx.y * 256 + wv * 64;

  float4_t C[4][4];
#pragma unroll
  for (int i = 0; i < 4; ++i)
#pragma unroll
    for (int j = 0; j < 4; ++j) C[i][j] = (float4_t){0.f, 0.f, 0.f, 0.f};

  for (int k0 = 0; k0 < KD; k0 += 32) {
    half8_t A[4], Bf[4];
#pragma unroll
    for (int i = 0; i < 4; ++i)
      A[i] = *(const half8_t*)&Ph[(size_t)(mw + 16 * i + l15) * KD + k0 + quad * 8];
#pragma unroll
    for (int j = 0; j < 4; ++j)
      Bf[j] = *(const half8_t*)&Woh[(size_t)(n0 + 16 * j + l15) * KD + k0 + quad * 8];
#pragma unroll
    for (int i = 0; i < 4; ++i)
#pragma unroll
      for (int j = 0; j < 4; ++j)
        C[i][j] = __builtin_amdgcn_mfma_f32_16x16x32_f16(A[i], Bf[j], C[i][j], 0, 0, 0);
  }

#pragma unroll
  for (int i = 0; i < 4; ++i)
#pragma unroll
    for (int j = 0; j < 4; ++j)
#pragma unroll
      for (int r = 0; r < 4; ++r)
        out[(size_t)(mw + 16 * i + quad * 4 + r) * En + n0 + 16 * j + l15] =
            C[i][j][r];
}

// ---------- MFMA flash attention: wave = 4 q-tiles (64 q) x 32-key rounds ----------
// No-max softmax (exp2 domain, scale*log2e folded into Q); zero cross-lane ops in
// k-loop; register double-buffer prefetch; tiled VT (one 2KB page per round);
// tail-mask HOISTED to a wave-uniform branch; f16 partials.
// XCD-locality swizzle: head h pinned to XCD h (8 heads = 8 XCDs), each XCD gets
// all 4 batches (load-balanced over varying L). Per-XCD K+V+Q working set = 1.5 MB
// << 4 MB L2, so per-round K/V re-reads hit local L2 instead of Infinity Cache.
__global__ __launch_bounds__(256) void attn_kernel(
    const _Float16* __restrict__ Qh, const _Float16* __restrict__ Kh,
    const _Float16* __restrict__ Vt, const int* __restrict__ len,
    _Float16* __restrict__ pacc, float* __restrict__ pl) {
  // bijective remap of the 4096-block grid: lid = (((b<<7)|inner)<<3)|h
  const int lid = blockIdx.x + 128 * (blockIdx.y + 8 * blockIdx.z);
  const int h = lid & 7;               // XCD id under default round-robin
  const int w = lid >> 3;              // 0..511 within this XCD
  const int b = w >> 7;                // all 4 batches on every XCD
  const int inner = w & 127;
  const int split = inner & (NS - 1);
  const int qg = inner >> 4;

  const int L = len[b];
  const int lane = threadIdx.x & 63;
  const int wv = threadIdx.x >> 6;     // 4 waves/block, independent 64-query tiles
  const int q0 = (qg * 4 + wv) * 64;
  if (q0 >= L) return;                 // wave-uniform exit (no LDS/barriers)
  const int ks = split * CHUNK;
  if (ks >= L) return;
  const int ke = min(L, ks + CHUNK);

  const int quad = lane >> 4;
  const int l15 = lane & 15;
  const size_t bh = (size_t)(b * Hn + h) * Sn;
  const _Float16* Vt0 = &Vt[(size_t)(b * Hn + h) * (Sn * Dn)];

  half8_t qf[4];
#pragma unroll
  for (int t = 0; t < 4; ++t)
    qf[t] = *(const half8_t*)&Qh[(bh + q0 + 16 * t + l15) * Dn + quad * 8];

  float4_t o0[4], o1[4];
  float ll[4];
#pragma unroll
  for (int t = 0; t < 4; ++t) {
    o0[t] = (float4_t){0.f, 0.f, 0.f, 0.f};
    o1[t] = (float4_t){0.f, 0.f, 0.f, 0.f};
    ll[t] = 0.f;
  }

  // V tile offsets within a 32x32 tile (1024 halfs): [d][k&31]
  const int vo0 = l15 * 32 + quad * 4;          // d=l15,     keys 0..15 half
  const int vo1 = (l15 + 16) * 32 + quad * 4;   // d=l15+16

  // ---- prefetch round 0 ----
  const _Float16* vt_c = &Vt0[(size_t)(ks >> 5) * 1024];
  half8_t kfc0 = *(const half8_t*)&Kh[(bh + ks + l15) * Dn + quad * 8];
  half8_t kfc1 = *(const half8_t*)&Kh[(bh + ks + 16 + l15) * Dn + quad * 8];
  half4_t v0c = *(const half4_t*)&vt_c[vo0];
  half4_t v1c = *(const half4_t*)&vt_c[vo1];
  half4_t v2c = *(const half4_t*)&vt_c[vo0 + 16];
  half4_t v3c = *(const half4_t*)&vt_c[vo1 + 16];

  for (int k0 = ks; k0 < ke; k0 += 32) {
    // ---- prefetch next round (clamped address, data discarded on last iter) ----
    const int kn = (k0 + 32 < ke) ? k0 + 32 : ks;
    const _Float16* vt_n = &Vt0[(size_t)(kn >> 5) * 1024];
    const half8_t kfn0 = *(const half8_t*)&Kh[(bh + kn + l15) * Dn + quad * 8];
    const half8_t kfn1 = *(const half8_t*)&Kh[(bh + kn + 16 + l15) * Dn + quad * 8];
    const half4_t v0n = *(const half4_t*)&vt_n[vo0];
    const half4_t v1n = *(const half4_t*)&vt_n[vo1];
    const half4_t v2n = *(const half4_t*)&vt_n[vo0 + 16];
    const half4_t v3n = *(const half4_t*)&vt_n[vo1 + 16];

    // ---- QK: 8 MFMA, 4 independent accumulator streams ----
    float4_t st0[4], st1[4];
#pragma unroll
    for (int t = 0; t < 4; ++t) {
      st0[t] = (float4_t){0.f, 0.f, 0.f, 0.f};
      st1[t] = (float4_t){0.f, 0.f, 0.f, 0.f};
      st0[t] = __builtin_amdgcn_mfma_f32_16x16x32_f16(kfc0, qf[t], st0[t], 0, 0, 0);
      st1[t] = __builtin_amdgcn_mfma_f32_16x16x32_f16(kfc1, qf[t], st1[t], 0, 0, 0);
    }

    // ---- p = exp2(s), per-lane l, PV: 16 MFMA. Tail masks only in last round ----
    if (k0 + 32 <= ke) {               // full round (hot path, wave-uniform)
#pragma unroll
      for (int t = 0; t < 4; ++t) {
        half4_t pf0, pf1;
#pragma unroll
        for (int r = 0; r < 4; ++r) {
          const float pa = __builtin_amdgcn_exp2f(st0[t][r]);
          const float pb = __builtin_amdgcn_exp2f(st1[t][r]);
          ll[t] += pa + pb;
          pf0[r] = (_Float16)pa;
          pf1[r] = (_Float16)pb;
        }
        o0[t] = __builtin_amdgcn_mfma_f32_16x16x16f16(pf0, v0c, o0[t], 0, 0, 0);
        o1[t] = __builtin_amdgcn_mfma_f32_16x16x16f16(pf0, v1c, o1[t], 0, 0, 0);
        o0[t] = __builtin_amdgcn_mfma_f32_16x16x16f16(pf1, v2c, o0[t], 0, 0, 0);
        o1[t] = __builtin_amdgcn_mfma_f32_16x16x16f16(pf1, v3c, o1[t], 0, 0, 0);
      }
    } else {                           // final partial round
      const int ka = k0 + quad * 4, kb = k0 + 16 + quad * 4;
#pragma unroll
      for (int t = 0; t < 4; ++t) {
        half4_t pf0, pf1;
#pragma unroll
        for (int r = 0; r < 4; ++r) {
          const float pa = __builtin_amdgcn_exp2f((ka + r < ke) ? st0[t][r] : -3.0e38f);
          const float pb = __builtin_amdgcn_exp2f((kb + r < ke) ? st1[t][r] : -3.0e38f);
          ll[t] += pa + pb;
          pf0[r] = (_Float16)pa;
          pf1[r] = (_Float16)pb;
        }
        o0[t] = __builtin_amdgcn_mfma_f32_16x16x16f16(pf0, v0c, o0[t], 0, 0, 0);
        o1[t] = __builtin_amdgcn_mfma_f32_16x16x16f16(pf0, v1c, o1[t], 0, 0, 0);
        o0[t] = __builtin_amdgcn_mfma_f32_16x16x16f16(pf1, v2c, o0[t], 0, 0, 0);
        o1[t] = __builtin_amdgcn_mfma_f32_16x16x16f16(pf1, v3c, o1[t], 0, 0, 0);
      }
    }
    kfc0 = kfn0; kfc1 = kfn1;
    v0c = v0n; v1c = v1n; v2c = v2n; v3c = v3n;
  }

  // ---- one l-reduction for the whole kernel (lane bits 4,5 = quads) ----
#pragma unroll
  for (int t = 0; t < 4; ++t) {
    ll[t] += __shfl_xor(ll[t], 16);
    ll[t] += __shfl_xor(ll[t], 32);
  }

  const size_t idx0 = ((size_t)(b * Hn + h) * NS + split) * Sn + q0;
#pragma unroll
  for (int t = 0; t < 4; ++t) {
#pragma unroll
    for (int r = 0; r < 4; ++r) {
      _Float16* pp = &pacc[(idx0 + 16 * t + quad * 4 + r) * 32];
      pp[l15] = (_Float16)o0[t][r];
      pp[l15 + 16] = (_Float16)o1[t][r];
    }
  }
  if (quad == 0) {  // lanes 0..15 hold l for q = q0+16t+l15
#pragma unroll
    for (int t = 0; t < 4; ++t) pl[idx0 + 16 * t + l15] = ll[t];
  }
}

// ---------- merge key-splits (plain sums, f16 partials) + fused tail-zero ----------
__global__ __launch_bounds__(256) void combine_kernel(const _Float16* __restrict__ pacc,
                                                      const float* __restrict__ pl,
                                                      const int* __restrict__ len,
                                                      _Float16* __restrict__ Ph) {
  const int b = blockIdx.z;
  const int L = len[b];
  if (blockIdx.y == Hn) {  // tail-zero slice: [L*En, Sn*En) as aligned half8s
    _Float16* base = Ph + (size_t)b * Sn * En;
    const size_t end = (size_t)Sn * En;
    const size_t stride = (size_t)gridDim.x * 256 * 8;
    half8_t z = {0, 0, 0, 0, 0, 0, 0, 0};
    for (size_t idx = (size_t)L * En + ((size_t)blockIdx.x * 256 + threadIdx.x) * 8;
         idx < end; idx += stride)
      *(half8_t*)&base[idx] = z;
    return;
  }
  const int h = blockIdx.y;
  const int q = blockIdx.x * 256 + threadIdx.x;
  if (q >= L) return;
  const size_t base = (size_t)(b * Hn + h) * NS * Sn;

  float T = 0.f;
  float o[32];
#pragma unroll
  for (int d = 0; d < 32; ++d) o[d] = 0.f;
#pragma unroll
  for (int sp = 0; sp < NS; ++sp) {
    if (sp * CHUNK < L) {
      T += pl[base + (size_t)sp * Sn + q];
      const half8_t* pp = (const half8_t*)&pacc[(base + (size_t)sp * Sn + q) * 32];
#pragma unroll
      for (int i = 0; i < 4; ++i) {
        half8_t v = pp[i];
#pragma unroll
        for (int t2 = 0; t2 < 8; ++t2) o[i * 8 + t2] += (float)v[t2];
      }
    }
  }
  const float inv = 1.0f / T;
  _Float16* dst = &Ph[(size_t)b * Sn * En + (size_t)h * L * Dn + (size_t)q * Dn];
#pragma unroll
  for (int i = 0; i < 4; ++i) {
    half8_t hv;
#pragma unroll
    for (int t2 = 0; t2 < 8; ++t2) hv[t2] = (_Float16)(o[i * 8 + t2] * inv);
    *(half8_t*)&dst[i * 8] = hv;
  }
}

extern "C" void kernel_launch(void* const* d_in, const int* in_sizes, int n_in,
                              void* d_out, int out_size, void* d_ws, size_t ws_size,
                              hipStream_t stream) {
  (void)in_sizes; (void)n_in; (void)out_size; (void)ws_size;
  const float* x  = (const float*)d_in[0];  // fp32 (B,S,E)
  const int* mask = (const int*)d_in[1];    // int32 (B,S)
  const float* Wq = (const float*)d_in[2];  // fp32 (E,E)
  const float* Wk = (const float*)d_in[3];
  const float* Wv = (const float*)d_in[4];
  const float* Wo = (const float*)d_in[5];
  float* out = (float*)d_out;               // fp32 (B,S,E)

  // ws: lengths | xh | Wh | Qh | Kh | Vt | Ph | pacc(f16) | pl  (~92 MB)
  float* wsf = (float*)d_ws;
  int* lengths = (int*)d_ws;
  const size_t BHSD = (size_t)Bn * Hn * Sn * Dn;  // 2,097,152
  _Float16* xh = (_Float16*)(wsf + 64);
  _Float16* Wh = xh + BHSD;                 // 4 x 65536
  _Float16* Qh = Wh + 4 * 65536;
  _Float16* Kh = Qh + BHSD;
  _Float16* Vt = Kh + BHSD;
  _Float16* Ph = Vt + BHSD;
  _Float16* pacc = Ph + BHSD;               // B*H*NS*Sn*32 halfs = 67 MB
  float* pl = (float*)(pacc + (size_t)Bn * Hn * NS * Sn * 32);

  len_kernel<<<dim3(Bn), 256, 0, stream>>>(mask, lengths);
  cvt_kernel<<<dim3((2097152 + 262144) / (256 * 8)), 256, 0, stream>>>(
      x, Wq, Wk, Wv, Wo, xh, Wh);
  qkv_gemm<<<dim3(12, 32), 256, 0, stream>>>(xh, Wh, Qh, Kh, Vt);
  attn_kernel<<<dim3((Sn / 256) * NS, Hn, Bn), 256, 0, stream>>>(
      Qh, Kh, Vt, lengths, pacc, pl);
  combine_kernel<<<dim3(Sn / 256, Hn + 1, Bn), 256, 0, stream>>>(
      pacc, pl, lengths, Ph);
  out_gemm<<<dim3(4, 32), 256, 0, stream>>>(Ph, Wh + 3 * 65536, out);
}

// Round 2
// 140.357 us; speedup vs baseline: 1.0752x; 1.0039x over previous
//
#include <hip/hip_runtime.h>
#include <cmath>

// Problem constants
#define Bn 4
#define Sn 2048
#define En 256
#define Hn 8
#define Dn 32
#define KD 256          // inner GEMM dim (= En)
#define NS 16           // key splits for attention
#define CHUNK 128       // keys per split

static constexpr float SCALE_F = 0.17677669529663687f;  // 32^-0.5
// SCALE * log2(e): Q is pre-scaled so attn can use raw v_exp_f32 (exp2)
static constexpr float SCALE_LOG2E = 0.25504210472155044f;

typedef _Float16 half4_t __attribute__((ext_vector_type(4)));
typedef _Float16 half8_t __attribute__((ext_vector_type(8)));
typedef float float4_t __attribute__((ext_vector_type(4)));

// ---------- fp32 -> f16 convert: x (2M) then Wq|Wk|Wv|Wo (64K each) ----------
// Fused: last block computes lengths[b] = sum(mask[b,:]) (one wave per batch).
__global__ __launch_bounds__(256) void cvt_kernel(
    const float* __restrict__ x, const float* __restrict__ Wq,
    const float* __restrict__ Wk, const float* __restrict__ Wv,
    const float* __restrict__ Wo, const int* __restrict__ mask,
    _Float16* __restrict__ xh, _Float16* __restrict__ Wh,
    int* __restrict__ len) {
  if (blockIdx.x == 1152) {  // lengths block: wave w sums batch w's mask
    const int b = threadIdx.x >> 6, lane = threadIdx.x & 63;
    int s = 0;
    for (int i = lane; i < Sn; i += 64) s += mask[b * Sn + i];
#pragma unroll
    for (int off = 32; off > 0; off >>= 1) s += __shfl_down(s, off, 64);
    if (lane == 0) len[b] = s;
    return;
  }
  const size_t base = ((size_t)blockIdx.x * 256 + threadIdx.x) * 8;
  const float* src; _Float16* dst; size_t off;
  if (base < 2097152) { src = x; dst = xh; off = base; }
  else {
    size_t wi = base - 2097152;        // 0 .. 262143
    int w = (int)(wi >> 16);           // 0..3
    off = wi & 65535;
    src = (w == 0) ? Wq : (w == 1) ? Wk : (w == 2) ? Wv : Wo;
    dst = Wh + (size_t)w * 65536;
  }
  float4 a = *(const float4*)&src[off];
  float4 b2 = *(const float4*)&src[off + 4];
  half8_t h;
  h[0] = (_Float16)a.x;  h[1] = (_Float16)a.y;
  h[2] = (_Float16)a.z;  h[3] = (_Float16)a.w;
  h[4] = (_Float16)b2.x; h[5] = (_Float16)b2.y;
  h[6] = (_Float16)b2.z; h[7] = (_Float16)b2.w;
  *(half8_t*)&dst[off] = h;
}

// ---------- QKV MFMA GEMM: [8192,256]f16 @ [768,256]^T f16 ----------
// V written in TILED transpose layout: VT[bh][kblk][d][k&31] (2KB tiles).
// XCD swizzle: 384 blocks = 8 XCDs x 48; each XCD gets 4 contiguous m-blocks
// (A-panel 512 KB) x all 12 n-blocks (B 384 KB) -> panels L2-resident per XCD.
__global__ __launch_bounds__(256) void qkv_gemm(
    const _Float16* __restrict__ xh, const _Float16* __restrict__ Wh,
    _Float16* __restrict__ Qh, _Float16* __restrict__ Kh,
    _Float16* __restrict__ Vt) {
  const int lane = threadIdx.x & 63;
  const int wv = threadIdx.x >> 6;
  const int quad = lane >> 4, l15 = lane & 15;
  const int fid = blockIdx.x + 12 * blockIdx.y;   // hw dispatch order
  const int wl = (fid & 7) * 48 + (fid >> 3);     // bijective (384 = 8*48)
  const int nb = wl % 12, mb = wl / 12;
  const int n0 = nb * 64;                  // matrix = n0>>8, uniform per block
  const int mw = mb * 256 + wv * 64;

  float4_t C[4][4];
#pragma unroll
  for (int i = 0; i < 4; ++i)
#pragma unroll
    for (int j = 0; j < 4; ++j) C[i][j] = (float4_t){0.f, 0.f, 0.f, 0.f};

  for (int k0 = 0; k0 < KD; k0 += 32) {
    half8_t A[4], Bf[4];
#pragma unroll
    for (int i = 0; i < 4; ++i)
      A[i] = *(const half8_t*)&xh[(size_t)(mw + 16 * i + l15) * KD + k0 + quad * 8];
#pragma unroll
    for (int j = 0; j < 4; ++j)
      Bf[j] = *(const half8_t*)&Wh[(size_t)(n0 + 16 * j + l15) * KD + k0 + quad * 8];
#pragma unroll
    for (int i = 0; i < 4; ++i)
#pragma unroll
      for (int j = 0; j < 4; ++j)
        C[i][j] = __builtin_amdgcn_mfma_f32_16x16x32_f16(A[i], Bf[j], C[i][j], 0, 0, 0);
  }

  const int mat = n0 >> 8;
  if (mat < 2) {
    _Float16* dstH = mat ? Kh : Qh;
    const float scale = mat ? 1.0f : SCALE_LOG2E;  // fold softmax scale * log2e into Q
#pragma unroll
    for (int i = 0; i < 4; ++i)
#pragma unroll
      for (int j = 0; j < 4; ++j) {
        const int c = ((n0 + 16 * j) & 255) + l15;
        const int h = c >> 5, d = c & 31;
#pragma unroll
        for (int r = 0; r < 4; ++r) {
          const int m = mw + 16 * i + quad * 4 + r;
          const int b = m >> 11, s = m & (Sn - 1);
          dstH[((size_t)(b * Hn + h) * Sn + s) * Dn + d] =
              (_Float16)(C[i][j][r] * scale);
        }
      }
  } else {
#pragma unroll
    for (int i = 0; i < 4; ++i)
#pragma unroll
      for (int j = 0; j < 4; ++j) {
        const int c = ((n0 + 16 * j) & 255) + l15;
        const int h = c >> 5, d = c & 31;
        const int m = mw + 16 * i + quad * 4;   // 4 consecutive s, same 32-tile
        const int b = m >> 11, s = m & (Sn - 1);
        half4_t hv;
#pragma unroll
        for (int r = 0; r < 4; ++r) hv[r] = (_Float16)C[i][j][r];
        *(half4_t*)&Vt[(size_t)(b * Hn + h) * (Sn * Dn) +
                       (size_t)(s >> 5) * 1024 + d * 32 + (s & 31)] = hv;
      }
  }
}

// ---------- output MFMA GEMM: [8192,256]f16 (Ph) @ Wo^T f16 -> fp32 d_out ----------
// XCD swizzle: 128 blocks = 8 XCDs x 16; each XCD: 4 m-blocks (Ph 512 KB) + Wo 128 KB.
__global__ __launch_bounds__(256) void out_gemm(
    const _Float16* __restrict__ Ph, const _Float16* __restrict__ Woh,
    float* __restrict__ out) {
  const int lane = threadIdx.x & 63;
  const int wv = threadIdx.x >> 6;
  const int quad = lane >> 4, l15 = lane & 15;
  const int fid = blockIdx.x + 4 * blockIdx.y;    // hw dispatch order
  const int wl = (fid & 7) * 16 + (fid >> 3);     // bijective (128 = 8*16)
  const int nb = wl % 4, mb = wl / 4;
  const int n0 = nb * 64;
  const int mw = mb * 256 + wv * 64;

  float4_t C[4][4];
#pragma unroll
  for (int i = 0; i < 4; ++i)
#pragma unroll
    for (int j = 0; j < 4; ++j) C[i][j] = (float4_t){0.f, 0.f, 0.f, 0.f};

  for (int k0 = 0; k0 < KD; k0 += 32) {
    half8_t A[4], Bf[4];
#pragma unroll
    for (int i = 0; i < 4; ++i)
      A[i] = *(const half8_t*)&Ph[(size_t)(mw + 16 * i + l15) * KD + k0 + quad * 8];
#pragma unroll
    for (int j = 0; j < 4; ++j)
      Bf[j] = *(const half8_t*)&Woh[(size_t)(n0 + 16 * j + l15) * KD + k0 + quad * 8];
#pragma unroll
    for (int i = 0; i < 4; ++i)
#pragma unroll
      for (int j = 0; j < 4; ++j)
        C[i][j] = __builtin_amdgcn_mfma_f32_16x16x32_f16(A[i], Bf[j], C[i][j], 0, 0, 0);
  }

#pragma unroll
  for (int i = 0; i < 4; ++i)
#pragma unroll
    for (int j = 0; j < 4; ++j)
#pragma unroll
      for (int r = 0; r < 4; ++r)
        out[(size_t)(mw + 16 * i + quad * 4 + r) * En + n0 + 16 * j + l15] =
            C[i][j][r];
}

// ---------- MFMA flash attention: wave = 4 q-tiles (64 q) x 32-key rounds ----------
// No-max softmax (exp2 domain, scale*log2e folded into Q); zero cross-lane ops in
// k-loop; register double-buffer prefetch; tiled VT (one 2KB page per round);
// tail-mask HOISTED to a wave-uniform branch; f16 partials.
// XCD-locality swizzle: head h pinned to XCD h (8 heads = 8 XCDs), each XCD gets
// all 4 batches (load-balanced over varying L). Per-XCD K+V+Q working set = 1.5 MB
// << 4 MB L2, so per-round K/V re-reads hit local L2 instead of Infinity Cache.
__global__ __launch_bounds__(256) void attn_kernel(
    const _Float16* __restrict__ Qh, const _Float16* __restrict__ Kh,
    const _Float16* __restrict__ Vt, const int* __restrict__ len,
    _Float16* __restrict__ pacc, float* __restrict__ pl) {
  // bijective remap of the 4096-block grid: lid = (((b<<7)|inner)<<3)|h
  const int lid = blockIdx.x + 128 * (blockIdx.y + 8 * blockIdx.z);
  const int h = lid & 7;               // XCD id under default round-robin
  const int w = lid >> 3;              // 0..511 within this XCD
  const int b = w >> 7;                // all 4 batches on every XCD
  const int inner = w & 127;
  const int split = inner & (NS - 1);
  const int qg = inner >> 4;

  const int L = len[b];
  const int lane = threadIdx.x & 63;
  const int wv = threadIdx.x >> 6;     // 4 waves/block, independent 64-query tiles
  const int q0 = (qg * 4 + wv) * 64;
  if (q0 >= L) return;                 // wave-uniform exit (no LDS/barriers)
  const int ks = split * CHUNK;
  if (ks >= L) return;
  const int ke = min(L, ks + CHUNK);

  const int quad = lane >> 4;
  const int l15 = lane & 15;
  const size_t bh = (size_t)(b * Hn + h) * Sn;
  const _Float16* Vt0 = &Vt[(size_t)(b * Hn + h) * (Sn * Dn)];

  half8_t qf[4];
#pragma unroll
  for (int t = 0; t < 4; ++t)
    qf[t] = *(const half8_t*)&Qh[(bh + q0 + 16 * t + l15) * Dn + quad * 8];

  float4_t o0[4], o1[4];
  float ll[4];
#pragma unroll
  for (int t = 0; t < 4; ++t) {
    o0[t] = (float4_t){0.f, 0.f, 0.f, 0.f};
    o1[t] = (float4_t){0.f, 0.f, 0.f, 0.f};
    ll[t] = 0.f;
  }

  // V tile offsets within a 32x32 tile (1024 halfs): [d][k&31]
  const int vo0 = l15 * 32 + quad * 4;          // d=l15,     keys 0..15 half
  const int vo1 = (l15 + 16) * 32 + quad * 4;   // d=l15+16

  // ---- prefetch round 0 ----
  const _Float16* vt_c = &Vt0[(size_t)(ks >> 5) * 1024];
  half8_t kfc0 = *(const half8_t*)&Kh[(bh + ks + l15) * Dn + quad * 8];
  half8_t kfc1 = *(const half8_t*)&Kh[(bh + ks + 16 + l15) * Dn + quad * 8];
  half4_t v0c = *(const half4_t*)&vt_c[vo0];
  half4_t v1c = *(const half4_t*)&vt_c[vo1];
  half4_t v2c = *(const half4_t*)&vt_c[vo0 + 16];
  half4_t v3c = *(const half4_t*)&vt_c[vo1 + 16];

  for (int k0 = ks; k0 < ke; k0 += 32) {
    // ---- prefetch next round (clamped address, data discarded on last iter) ----
    const int kn = (k0 + 32 < ke) ? k0 + 32 : ks;
    const _Float16* vt_n = &Vt0[(size_t)(kn >> 5) * 1024];
    const half8_t kfn0 = *(const half8_t*)&Kh[(bh + kn + l15) * Dn + quad * 8];
    const half8_t kfn1 = *(const half8_t*)&Kh[(bh + kn + 16 + l15) * Dn + quad * 8];
    const half4_t v0n = *(const half4_t*)&vt_n[vo0];
    const half4_t v1n = *(const half4_t*)&vt_n[vo1];
    const half4_t v2n = *(const half4_t*)&vt_n[vo0 + 16];
    const half4_t v3n = *(const half4_t*)&vt_n[vo1 + 16];

    // ---- QK: 8 MFMA, 4 independent accumulator streams ----
    float4_t st0[4], st1[4];
#pragma unroll
    for (int t = 0; t < 4; ++t) {
      st0[t] = (float4_t){0.f, 0.f, 0.f, 0.f};
      st1[t] = (float4_t){0.f, 0.f, 0.f, 0.f};
      st0[t] = __builtin_amdgcn_mfma_f32_16x16x32_f16(kfc0, qf[t], st0[t], 0, 0, 0);
      st1[t] = __builtin_amdgcn_mfma_f32_16x16x32_f16(kfc1, qf[t], st1[t], 0, 0, 0);
    }

    // ---- p = exp2(s), per-lane l, PV: 16 MFMA. Tail masks only in last round ----
    if (k0 + 32 <= ke) {               // full round (hot path, wave-uniform)
#pragma unroll
      for (int t = 0; t < 4; ++t) {
        half4_t pf0, pf1;
#pragma unroll
        for (int r = 0; r < 4; ++r) {
          const float pa = __builtin_amdgcn_exp2f(st0[t][r]);
          const float pb = __builtin_amdgcn_exp2f(st1[t][r]);
          ll[t] += pa + pb;
          pf0[r] = (_Float16)pa;
          pf1[r] = (_Float16)pb;
        }
        o0[t] = __builtin_amdgcn_mfma_f32_16x16x16f16(pf0, v0c, o0[t], 0, 0, 0);
        o1[t] = __builtin_amdgcn_mfma_f32_16x16x16f16(pf0, v1c, o1[t], 0, 0, 0);
        o0[t] = __builtin_amdgcn_mfma_f32_16x16x16f16(pf1, v2c, o0[t], 0, 0, 0);
        o1[t] = __builtin_amdgcn_mfma_f32_16x16x16f16(pf1, v3c, o1[t], 0, 0, 0);
      }
    } else {                           // final partial round
      const int ka = k0 + quad * 4, kb = k0 + 16 + quad * 4;
#pragma unroll
      for (int t = 0; t < 4; ++t) {
        half4_t pf0, pf1;
#pragma unroll
        for (int r = 0; r < 4; ++r) {
          const float pa = __builtin_amdgcn_exp2f((ka + r < ke) ? st0[t][r] : -3.0e38f);
          const float pb = __builtin_amdgcn_exp2f((kb + r < ke) ? st1[t][r] : -3.0e38f);
          ll[t] += pa + pb;
          pf0[r] = (_Float16)pa;
          pf1[r] = (_Float16)pb;
        }
        o0[t] = __builtin_amdgcn_mfma_f32_16x16x16f16(pf0, v0c, o0[t], 0, 0, 0);
        o1[t] = __builtin_amdgcn_mfma_f32_16x16x16f16(pf0, v1c, o1[t], 0, 0, 0);
        o0[t] = __builtin_amdgcn_mfma_f32_16x16x16f16(pf1, v2c, o0[t], 0, 0, 0);
        o1[t] = __builtin_amdgcn_mfma_f32_16x16x16f16(pf1, v3c, o1[t], 0, 0, 0);
      }
    }
    kfc0 = kfn0; kfc1 = kfn1;
    v0c = v0n; v1c = v1n; v2c = v2n; v3c = v3n;
  }

  // ---- one l-reduction for the whole kernel (lane bits 4,5 = quads) ----
#pragma unroll
  for (int t = 0; t < 4; ++t) {
    ll[t] += __shfl_xor(ll[t], 16);
    ll[t] += __shfl_xor(ll[t], 32);
  }

  const size_t idx0 = ((size_t)(b * Hn + h) * NS + split) * Sn + q0;
#pragma unroll
  for (int t = 0; t < 4; ++t) {
#pragma unroll
    for (int r = 0; r < 4; ++r) {
      _Float16* pp = &pacc[(idx0 + 16 * t + quad * 4 + r) * 32];
      pp[l15] = (_Float16)o0[t][r];
      pp[l15 + 16] = (_Float16)o1[t][r];
    }
  }
  if (quad == 0) {  // lanes 0..15 hold l for q = q0+16t+l15
#pragma unroll
    for (int t = 0; t < 4; ++t) pl[idx0 + 16 * t + l15] = ll[t];
  }
}

// ---------- merge key-splits (plain sums, f16 partials) + fused tail-zero ----------
__global__ __launch_bounds__(256) void combine_kernel(const _Float16* __restrict__ pacc,
                                                      const float* __restrict__ pl,
                                                      const int* __restrict__ len,
                                                      _Float16* __restrict__ Ph) {
  const int b = blockIdx.z;
  const int L = len[b];
  if (blockIdx.y == Hn) {  // tail-zero slice: [L*En, Sn*En) as aligned half8s
    _Float16* base = Ph + (size_t)b * Sn * En;
    const size_t end = (size_t)Sn * En;
    const size_t stride = (size_t)gridDim.x * 256 * 8;
    half8_t z = {0, 0, 0, 0, 0, 0, 0, 0};
    for (size_t idx = (size_t)L * En + ((size_t)blockIdx.x * 256 + threadIdx.x) * 8;
         idx < end; idx += stride)
      *(half8_t*)&base[idx] = z;
    return;
  }
  const int h = blockIdx.y;
  const int q = blockIdx.x * 256 + threadIdx.x;
  if (q >= L) return;
  const size_t base = (size_t)(b * Hn + h) * NS * Sn;

  float T = 0.f;
  float o[32];
#pragma unroll
  for (int d = 0; d < 32; ++d) o[d] = 0.f;
#pragma unroll
  for (int sp = 0; sp < NS; ++sp) {
    if (sp * CHUNK < L) {
      T += pl[base + (size_t)sp * Sn + q];
      const half8_t* pp = (const half8_t*)&pacc[(base + (size_t)sp * Sn + q) * 32];
#pragma unroll
      for (int i = 0; i < 4; ++i) {
        half8_t v = pp[i];
#pragma unroll
        for (int t2 = 0; t2 < 8; ++t2) o[i * 8 + t2] += (float)v[t2];
      }
    }
  }
  const float inv = 1.0f / T;
  _Float16* dst = &Ph[(size_t)b * Sn * En + (size_t)h * L * Dn + (size_t)q * Dn];
#pragma unroll
  for (int i = 0; i < 4; ++i) {
    half8_t hv;
#pragma unroll
    for (int t2 = 0; t2 < 8; ++t2) hv[t2] = (_Float16)(o[i * 8 + t2] * inv);
    *(half8_t*)&dst[i * 8] = hv;
  }
}

extern "C" void kernel_launch(void* const* d_in, const int* in_sizes, int n_in,
                              void* d_out, int out_size, void* d_ws, size_t ws_size,
                              hipStream_t stream) {
  (void)in_sizes; (void)n_in; (void)out_size; (void)ws_size;
  const float* x  = (const float*)d_in[0];  // fp32 (B,S,E)
  const int* mask = (const int*)d_in[1];    // int32 (B,S)
  const float* Wq = (const float*)d_in[2];  // fp32 (E,E)
  const float* Wk = (const float*)d_in[3];
  const float* Wv = (const float*)d_in[4];
  const float* Wo = (const float*)d_in[5];
  float* out = (float*)d_out;               // fp32 (B,S,E)

  // ws: lengths | xh | Wh | Qh | Kh | Vt | Ph | pacc(f16) | pl  (~92 MB)
  float* wsf = (float*)d_ws;
  int* lengths = (int*)d_ws;
  const size_t BHSD = (size_t)Bn * Hn * Sn * Dn;  // 2,097,152
  _Float16* xh = (_Float16*)(wsf + 64);
  _Float16* Wh = xh + BHSD;                 // 4 x 65536
  _Float16* Qh = Wh + 4 * 65536;
  _Float16* Kh = Qh + BHSD;
  _Float16* Vt = Kh + BHSD;
  _Float16* Ph = Vt + BHSD;
  _Float16* pacc = Ph + BHSD;               // B*H*NS*Sn*32 halfs = 67 MB
  float* pl = (float*)(pacc + (size_t)Bn * Hn * NS * Sn * 32);

  cvt_kernel<<<dim3((2097152 + 262144) / (256 * 8) + 1), 256, 0, stream>>>(
      x, Wq, Wk, Wv, Wo, mask, xh, Wh, lengths);
  qkv_gemm<<<dim3(12, 32), 256, 0, stream>>>(xh, Wh, Qh, Kh, Vt);
  attn_kernel<<<dim3((Sn / 256) * NS, Hn, Bn), 256, 0, stream>>>(
      Qh, Kh, Vt, lengths, pacc, pl);
  combine_kernel<<<dim3(Sn / 256, Hn + 1, Bn), 256, 0, stream>>>(
      pacc, pl, lengths, Ph);
  out_gemm<<<dim3(4, 32), 256, 0, stream>>>(Ph, Wh + 3 * 65536, out);
}

// Round 3
// 134.891 us; speedup vs baseline: 1.1187x; 1.0405x over previous
//
#include <hip/hip_runtime.h>
#include <cmath>

// Problem constants
#define Bn 4
#define Sn 2048
#define En 256
#define Hn 8
#define Dn 32
#define KD 256          // inner GEMM dim (= En)
#define NS 4            // key splits for attention
#define CHUNK 512       // keys per split (16 rounds of 32 keys per wave)

static constexpr float SCALE_F = 0.17677669529663687f;  // 32^-0.5
// SCALE * log2(e): Q is pre-scaled so attn can use raw v_exp_f32 (exp2)
static constexpr float SCALE_LOG2E = 0.25504210472155044f;

typedef _Float16 half4_t __attribute__((ext_vector_type(4)));
typedef _Float16 half8_t __attribute__((ext_vector_type(8)));
typedef float float4_t __attribute__((ext_vector_type(4)));

// ---------- fp32 -> f16 convert: x (2M) then Wq|Wk|Wv|Wo (64K each) ----------
// Fused: last block computes lengths[b] = sum(mask[b,:]) (one wave per batch).
__global__ __launch_bounds__(256) void cvt_kernel(
    const float* __restrict__ x, const float* __restrict__ Wq,
    const float* __restrict__ Wk, const float* __restrict__ Wv,
    const float* __restrict__ Wo, const int* __restrict__ mask,
    _Float16* __restrict__ xh, _Float16* __restrict__ Wh,
    int* __restrict__ len) {
  if (blockIdx.x == 1152) {  // lengths block: wave w sums batch w's mask
    const int b = threadIdx.x >> 6, lane = threadIdx.x & 63;
    int s = 0;
    for (int i = lane; i < Sn; i += 64) s += mask[b * Sn + i];
#pragma unroll
    for (int off = 32; off > 0; off >>= 1) s += __shfl_down(s, off, 64);
    if (lane == 0) len[b] = s;
    return;
  }
  const size_t base = ((size_t)blockIdx.x * 256 + threadIdx.x) * 8;
  const float* src; _Float16* dst; size_t off;
  if (base < 2097152) { src = x; dst = xh; off = base; }
  else {
    size_t wi = base - 2097152;        // 0 .. 262143
    int w = (int)(wi >> 16);           // 0..3
    off = wi & 65535;
    src = (w == 0) ? Wq : (w == 1) ? Wk : (w == 2) ? Wv : Wo;
    dst = Wh + (size_t)w * 65536;
  }
  float4 a = *(const float4*)&src[off];
  float4 b2 = *(const float4*)&src[off + 4];
  half8_t h;
  h[0] = (_Float16)a.x;  h[1] = (_Float16)a.y;
  h[2] = (_Float16)a.z;  h[3] = (_Float16)a.w;
  h[4] = (_Float16)b2.x; h[5] = (_Float16)b2.y;
  h[6] = (_Float16)b2.z; h[7] = (_Float16)b2.w;
  *(half8_t*)&dst[off] = h;
}

// ---------- QKV MFMA GEMM: [8192,256]f16 @ [768,256]^T f16 ----------
// V written in TILED transpose layout: VT[bh][kblk][d][k&31] (2KB tiles).
// XCD swizzle: 384 blocks = 8 XCDs x 48; each XCD gets 4 contiguous m-blocks
// (A-panel 512 KB) x all 12 n-blocks (B 384 KB) -> panels L2-resident per XCD.
__global__ __launch_bounds__(256) void qkv_gemm(
    const _Float16* __restrict__ xh, const _Float16* __restrict__ Wh,
    _Float16* __restrict__ Qh, _Float16* __restrict__ Kh,
    _Float16* __restrict__ Vt) {
  const int lane = threadIdx.x & 63;
  const int wv = threadIdx.x >> 6;
  const int quad = lane >> 4, l15 = lane & 15;
  const int fid = blockIdx.x + 12 * blockIdx.y;   // hw dispatch order
  const int wl = (fid & 7) * 48 + (fid >> 3);     // bijective (384 = 8*48)
  const int nb = wl % 12, mb = wl / 12;
  const int n0 = nb * 64;                  // matrix = n0>>8, uniform per block
  const int mw = mb * 256 + wv * 64;

  float4_t C[4][4];
#pragma unroll
  for (int i = 0; i < 4; ++i)
#pragma unroll
    for (int j = 0; j < 4; ++j) C[i][j] = (float4_t){0.f, 0.f, 0.f, 0.f};

  for (int k0 = 0; k0 < KD; k0 += 32) {
    half8_t A[4], Bf[4];
#pragma unroll
    for (int i = 0; i < 4; ++i)
      A[i] = *(const half8_t*)&xh[(size_t)(mw + 16 * i + l15) * KD + k0 + quad * 8];
#pragma unroll
    for (int j = 0; j < 4; ++j)
      Bf[j] = *(const half8_t*)&Wh[(size_t)(n0 + 16 * j + l15) * KD + k0 + quad * 8];
#pragma unroll
    for (int i = 0; i < 4; ++i)
#pragma unroll
      for (int j = 0; j < 4; ++j)
        C[i][j] = __builtin_amdgcn_mfma_f32_16x16x32_f16(A[i], Bf[j], C[i][j], 0, 0, 0);
  }

  const int mat = n0 >> 8;
  if (mat < 2) {
    _Float16* dstH = mat ? Kh : Qh;
    const float scale = mat ? 1.0f : SCALE_LOG2E;  // fold softmax scale * log2e into Q
#pragma unroll
    for (int i = 0; i < 4; ++i)
#pragma unroll
      for (int j = 0; j < 4; ++j) {
        const int c = ((n0 + 16 * j) & 255) + l15;
        const int h = c >> 5, d = c & 31;
#pragma unroll
        for (int r = 0; r < 4; ++r) {
          const int m = mw + 16 * i + quad * 4 + r;
          const int b = m >> 11, s = m & (Sn - 1);
          dstH[((size_t)(b * Hn + h) * Sn + s) * Dn + d] =
              (_Float16)(C[i][j][r] * scale);
        }
      }
  } else {
#pragma unroll
    for (int i = 0; i < 4; ++i)
#pragma unroll
      for (int j = 0; j < 4; ++j) {
        const int c = ((n0 + 16 * j) & 255) + l15;
        const int h = c >> 5, d = c & 31;
        const int m = mw + 16 * i + quad * 4;   // 4 consecutive s, same 32-tile
        const int b = m >> 11, s = m & (Sn - 1);
        half4_t hv;
#pragma unroll
        for (int r = 0; r < 4; ++r) hv[r] = (_Float16)C[i][j][r];
        *(half4_t*)&Vt[(size_t)(b * Hn + h) * (Sn * Dn) +
                       (size_t)(s >> 5) * 1024 + d * 32 + (s & 31)] = hv;
      }
  }
}

// ---------- output MFMA GEMM: [8192,256]f16 (Ph) @ Wo^T f16 -> fp32 d_out ----------
// XCD swizzle: 128 blocks = 8 XCDs x 16; each XCD: 4 m-blocks (Ph 512 KB) + Wo 128 KB.
__global__ __launch_bounds__(256) void out_gemm(
    const _Float16* __restrict__ Ph, const _Float16* __restrict__ Woh,
    float* __restrict__ out) {
  const int lane = threadIdx.x & 63;
  const int wv = threadIdx.x >> 6;
  const int quad = lane >> 4, l15 = lane & 15;
  const int fid = blockIdx.x + 4 * blockIdx.y;    // hw dispatch order
  const int wl = (fid & 7) * 16 + (fid >> 3);     // bijective (128 = 8*16)
  const int nb = wl % 4, mb = wl / 4;
  const int n0 = nb * 64;
  const int mw = mb * 256 + wv * 64;

  float4_t C[4][4];
#pragma unroll
  for (int i = 0; i < 4; ++i)
#pragma unroll
    for (int j = 0; j < 4; ++j) C[i][j] = (float4_t){0.f, 0.f, 0.f, 0.f};

  for (int k0 = 0; k0 < KD; k0 += 32) {
    half8_t A[4], Bf[4];
#pragma unroll
    for (int i = 0; i < 4; ++i)
      A[i] = *(const half8_t*)&Ph[(size_t)(mw + 16 * i + l15) * KD + k0 + quad * 8];
#pragma unroll
    for (int j = 0; j < 4; ++j)
      Bf[j] = *(const half8_t*)&Woh[(size_t)(n0 + 16 * j + l15) * KD + k0 + quad * 8];
#pragma unroll
    for (int i = 0; i < 4; ++i)
#pragma unroll
      for (int j = 0; j < 4; ++j)
        C[i][j] = __builtin_amdgcn_mfma_f32_16x16x32_f16(A[i], Bf[j], C[i][j], 0, 0, 0);
  }

#pragma unroll
  for (int i = 0; i < 4; ++i)
#pragma unroll
    for (int j = 0; j < 4; ++j)
#pragma unroll
      for (int r = 0; r < 4; ++r)
        out[(size_t)(mw + 16 * i + quad * 4 + r) * En + n0 + 16 * j + l15] =
            C[i][j][r];
}

// ---------- MFMA flash attention: wave = 4 q-tiles (64 q) x 32-key rounds ----------
// NS=4 split-K (CHUNK=512 -> up to 16 rounds/wave): prologue/epilogue amortized
// 4x vs NS=16, pacc traffic 4x smaller, waves live 4x longer (latency hidable).
// No-max softmax (exp2 domain, scale*log2e folded into Q); zero cross-lane ops in
// k-loop; register double-buffer prefetch; tiled VT (one 2KB page per round);
// tail-mask HOISTED to a wave-uniform branch; f16 partials.
// XCD-locality swizzle: head h pinned to XCD h (8 heads = 8 XCDs), each XCD gets
// all 4 batches (load-balanced over varying L). Per-XCD K+V+Q working set = 1.5 MB
// << 4 MB L2, so per-round K/V re-reads hit local L2 instead of Infinity Cache.
__global__ __launch_bounds__(256) void attn_kernel(
    const _Float16* __restrict__ Qh, const _Float16* __restrict__ Kh,
    const _Float16* __restrict__ Vt, const int* __restrict__ len,
    _Float16* __restrict__ pacc, float* __restrict__ pl) {
  // bijective remap of the 1024-block grid: lid = (((b<<5)|inner)<<3)|h
  const int lid = blockIdx.x + 32 * (blockIdx.y + 8 * blockIdx.z);
  const int h = lid & 7;               // XCD id under default round-robin
  const int w = lid >> 3;              // 0..127 within this XCD
  const int b = w >> 5;                // all 4 batches on every XCD
  const int inner = w & 31;
  const int split = inner & (NS - 1);
  const int qg = inner >> 2;           // 0..7

  const int L = len[b];
  const int lane = threadIdx.x & 63;
  const int wv = threadIdx.x >> 6;     // 4 waves/block, independent 64-query tiles
  const int q0 = (qg * 4 + wv) * 64;
  if (q0 >= L) return;                 // wave-uniform exit (no LDS/barriers)
  const int ks = split * CHUNK;
  if (ks >= L) return;
  const int ke = min(L, ks + CHUNK);

  const int quad = lane >> 4;
  const int l15 = lane & 15;
  const size_t bh = (size_t)(b * Hn + h) * Sn;
  const _Float16* Vt0 = &Vt[(size_t)(b * Hn + h) * (Sn * Dn)];

  half8_t qf[4];
#pragma unroll
  for (int t = 0; t < 4; ++t)
    qf[t] = *(const half8_t*)&Qh[(bh + q0 + 16 * t + l15) * Dn + quad * 8];

  float4_t o0[4], o1[4];
  float ll[4];
#pragma unroll
  for (int t = 0; t < 4; ++t) {
    o0[t] = (float4_t){0.f, 0.f, 0.f, 0.f};
    o1[t] = (float4_t){0.f, 0.f, 0.f, 0.f};
    ll[t] = 0.f;
  }

  // V tile offsets within a 32x32 tile (1024 halfs): [d][k&31]
  const int vo0 = l15 * 32 + quad * 4;          // d=l15,     keys 0..15 half
  const int vo1 = (l15 + 16) * 32 + quad * 4;   // d=l15+16

  // ---- prefetch round 0 ----
  const _Float16* vt_c = &Vt0[(size_t)(ks >> 5) * 1024];
  half8_t kfc0 = *(const half8_t*)&Kh[(bh + ks + l15) * Dn + quad * 8];
  half8_t kfc1 = *(const half8_t*)&Kh[(bh + ks + 16 + l15) * Dn + quad * 8];
  half4_t v0c = *(const half4_t*)&vt_c[vo0];
  half4_t v1c = *(const half4_t*)&vt_c[vo1];
  half4_t v2c = *(const half4_t*)&vt_c[vo0 + 16];
  half4_t v3c = *(const half4_t*)&vt_c[vo1 + 16];

  for (int k0 = ks; k0 < ke; k0 += 32) {
    // ---- prefetch next round (clamped address, data discarded on last iter) ----
    const int kn = (k0 + 32 < ke) ? k0 + 32 : ks;
    const _Float16* vt_n = &Vt0[(size_t)(kn >> 5) * 1024];
    const half8_t kfn0 = *(const half8_t*)&Kh[(bh + kn + l15) * Dn + quad * 8];
    const half8_t kfn1 = *(const half8_t*)&Kh[(bh + kn + 16 + l15) * Dn + quad * 8];
    const half4_t v0n = *(const half4_t*)&vt_n[vo0];
    const half4_t v1n = *(const half4_t*)&vt_n[vo1];
    const half4_t v2n = *(const half4_t*)&vt_n[vo0 + 16];
    const half4_t v3n = *(const half4_t*)&vt_n[vo1 + 16];

    // ---- QK: 8 MFMA, 4 independent accumulator streams ----
    float4_t st0[4], st1[4];
#pragma unroll
    for (int t = 0; t < 4; ++t) {
      st0[t] = (float4_t){0.f, 0.f, 0.f, 0.f};
      st1[t] = (float4_t){0.f, 0.f, 0.f, 0.f};
      st0[t] = __builtin_amdgcn_mfma_f32_16x16x32_f16(kfc0, qf[t], st0[t], 0, 0, 0);
      st1[t] = __builtin_amdgcn_mfma_f32_16x16x32_f16(kfc1, qf[t], st1[t], 0, 0, 0);
    }

    // ---- p = exp2(s), per-lane l, PV: 16 MFMA. Tail masks only in last round ----
    if (k0 + 32 <= ke) {               // full round (hot path, wave-uniform)
#pragma unroll
      for (int t = 0; t < 4; ++t) {
        half4_t pf0, pf1;
#pragma unroll
        for (int r = 0; r < 4; ++r) {
          const float pa = __builtin_amdgcn_exp2f(st0[t][r]);
          const float pb = __builtin_amdgcn_exp2f(st1[t][r]);
          ll[t] += pa + pb;
          pf0[r] = (_Float16)pa;
          pf1[r] = (_Float16)pb;
        }
        o0[t] = __builtin_amdgcn_mfma_f32_16x16x16f16(pf0, v0c, o0[t], 0, 0, 0);
        o1[t] = __builtin_amdgcn_mfma_f32_16x16x16f16(pf0, v1c, o1[t], 0, 0, 0);
        o0[t] = __builtin_amdgcn_mfma_f32_16x16x16f16(pf1, v2c, o0[t], 0, 0, 0);
        o1[t] = __builtin_amdgcn_mfma_f32_16x16x16f16(pf1, v3c, o1[t], 0, 0, 0);
      }
    } else {                           // final partial round
      const int ka = k0 + quad * 4, kb = k0 + 16 + quad * 4;
#pragma unroll
      for (int t = 0; t < 4; ++t) {
        half4_t pf0, pf1;
#pragma unroll
        for (int r = 0; r < 4; ++r) {
          const float pa = __builtin_amdgcn_exp2f((ka + r < ke) ? st0[t][r] : -3.0e38f);
          const float pb = __builtin_amdgcn_exp2f((kb + r < ke) ? st1[t][r] : -3.0e38f);
          ll[t] += pa + pb;
          pf0[r] = (_Float16)pa;
          pf1[r] = (_Float16)pb;
        }
        o0[t] = __builtin_amdgcn_mfma_f32_16x16x16f16(pf0, v0c, o0[t], 0, 0, 0);
        o1[t] = __builtin_amdgcn_mfma_f32_16x16x16f16(pf0, v1c, o1[t], 0, 0, 0);
        o0[t] = __builtin_amdgcn_mfma_f32_16x16x16f16(pf1, v2c, o0[t], 0, 0, 0);
        o1[t] = __builtin_amdgcn_mfma_f32_16x16x16f16(pf1, v3c, o1[t], 0, 0, 0);
      }
    }
    kfc0 = kfn0; kfc1 = kfn1;
    v0c = v0n; v1c = v1n; v2c = v2n; v3c = v3n;
  }

  // ---- one l-reduction for the whole kernel (lane bits 4,5 = quads) ----
#pragma unroll
  for (int t = 0; t < 4; ++t) {
    ll[t] += __shfl_xor(ll[t], 16);
    ll[t] += __shfl_xor(ll[t], 32);
  }

  const size_t idx0 = ((size_t)(b * Hn + h) * NS + split) * Sn + q0;
#pragma unroll
  for (int t = 0; t < 4; ++t) {
#pragma unroll
    for (int r = 0; r < 4; ++r) {
      _Float16* pp = &pacc[(idx0 + 16 * t + quad * 4 + r) * 32];
      pp[l15] = (_Float16)o0[t][r];
      pp[l15 + 16] = (_Float16)o1[t][r];
    }
  }
  if (quad == 0) {  // lanes 0..15 hold l for q = q0+16t+l15
#pragma unroll
    for (int t = 0; t < 4; ++t) pl[idx0 + 16 * t + l15] = ll[t];
  }
}

// ---------- merge key-splits (plain sums, f16 partials) + fused tail-zero ----------
__global__ __launch_bounds__(256) void combine_kernel(const _Float16* __restrict__ pacc,
                                                      const float* __restrict__ pl,
                                                      const int* __restrict__ len,
                                                      _Float16* __restrict__ Ph) {
  const int b = blockIdx.z;
  const int L = len[b];
  if (blockIdx.y == Hn) {  // tail-zero slice: [L*En, Sn*En) as aligned half8s
    _Float16* base = Ph + (size_t)b * Sn * En;
    const size_t end = (size_t)Sn * En;
    const size_t stride = (size_t)gridDim.x * 256 * 8;
    half8_t z = {0, 0, 0, 0, 0, 0, 0, 0};
    for (size_t idx = (size_t)L * En + ((size_t)blockIdx.x * 256 + threadIdx.x) * 8;
         idx < end; idx += stride)
      *(half8_t*)&base[idx] = z;
    return;
  }
  const int h = blockIdx.y;
  const int q = blockIdx.x * 256 + threadIdx.x;
  if (q >= L) return;
  const size_t base = (size_t)(b * Hn + h) * NS * Sn;

  float T = 0.f;
  float o[32];
#pragma unroll
  for (int d = 0; d < 32; ++d) o[d] = 0.f;
#pragma unroll
  for (int sp = 0; sp < NS; ++sp) {
    if (sp * CHUNK < L) {
      T += pl[base + (size_t)sp * Sn + q];
      const half8_t* pp = (const half8_t*)&pacc[(base + (size_t)sp * Sn + q) * 32];
#pragma unroll
      for (int i = 0; i < 4; ++i) {
        half8_t v = pp[i];
#pragma unroll
        for (int t2 = 0; t2 < 8; ++t2) o[i * 8 + t2] += (float)v[t2];
      }
    }
  }
  const float inv = 1.0f / T;
  _Float16* dst = &Ph[(size_t)b * Sn * En + (size_t)h * L * Dn + (size_t)q * Dn];
#pragma unroll
  for (int i = 0; i < 4; ++i) {
    half8_t hv;
#pragma unroll
    for (int t2 = 0; t2 < 8; ++t2) hv[t2] = (_Float16)(o[i * 8 + t2] * inv);
    *(half8_t*)&dst[i * 8] = hv;
  }
}

extern "C" void kernel_launch(void* const* d_in, const int* in_sizes, int n_in,
                              void* d_out, int out_size, void* d_ws, size_t ws_size,
                              hipStream_t stream) {
  (void)in_sizes; (void)n_in; (void)out_size; (void)ws_size;
  const float* x  = (const float*)d_in[0];  // fp32 (B,S,E)
  const int* mask = (const int*)d_in[1];    // int32 (B,S)
  const float* Wq = (const float*)d_in[2];  // fp32 (E,E)
  const float* Wk = (const float*)d_in[3];
  const float* Wv = (const float*)d_in[4];
  const float* Wo = (const float*)d_in[5];
  float* out = (float*)d_out;               // fp32 (B,S,E)

  // ws: lengths | xh | Wh | Qh | Kh | Vt | Ph | pacc(f16) | pl  (~38 MB)
  float* wsf = (float*)d_ws;
  int* lengths = (int*)d_ws;
  const size_t BHSD = (size_t)Bn * Hn * Sn * Dn;  // 2,097,152
  _Float16* xh = (_Float16*)(wsf + 64);
  _Float16* Wh = xh + BHSD;                 // 4 x 65536
  _Float16* Qh = Wh + 4 * 65536;
  _Float16* Kh = Qh + BHSD;
  _Float16* Vt = Kh + BHSD;
  _Float16* Ph = Vt + BHSD;
  _Float16* pacc = Ph + BHSD;               // B*H*NS*Sn*32 halfs = 16.8 MB
  float* pl = (float*)(pacc + (size_t)Bn * Hn * NS * Sn * 32);

  cvt_kernel<<<dim3((2097152 + 262144) / (256 * 8) + 1), 256, 0, stream>>>(
      x, Wq, Wk, Wv, Wo, mask, xh, Wh, lengths);
  qkv_gemm<<<dim3(12, 32), 256, 0, stream>>>(xh, Wh, Qh, Kh, Vt);
  attn_kernel<<<dim3((Sn / 256) * NS, Hn, Bn), 256, 0, stream>>>(
      Qh, Kh, Vt, lengths, pacc, pl);
  combine_kernel<<<dim3(Sn / 256, Hn + 1, Bn), 256, 0, stream>>>(
      pacc, pl, lengths, Ph);
  out_gemm<<<dim3(4, 32), 256, 0, stream>>>(Ph, Wh + 3 * 65536, out);
}